// Round 1
// baseline (68.384 us; speedup 1.0000x reference)
//
#include <hip/hip_runtime.h>

#define B_ 1024
#define N_ 20000
#define M_ 10000
#define K_ 8
#define CHK_W_ 8
#define OBS_W_ 200

constexpr float EPS_ = 1e-6f;
constexpr float LN2_ = 0.69314718055994530942f;

template <bool ATOMIC>
__global__ __launch_bounds__(256) void decode_loss_main(
    const float* __restrict__ llrs,
    const float* __restrict__ syndromes,
    const float* __restrict__ observables,
    const int*   __restrict__ chk_cols,
    const int*   __restrict__ obs_cols,
    float* __restrict__ part)   // per-block partials (or scalar out if ATOMIC)
{
    __shared__ _Float16 t_sh[N_];
    __shared__ float red[4];

    const int b   = blockIdx.x;
    const int tid = threadIdx.x;

    // Stage tanh(llr/2) row into LDS as fp16 (40 KB). float4-vectorized read.
    const float4* row4 = reinterpret_cast<const float4*>(llrs + (size_t)b * N_);
    for (int i = tid; i < N_ / 4; i += 256) {
        float4 v = row4[i];
        t_sh[4 * i + 0] = (_Float16)tanhf(0.5f * v.x);
        t_sh[4 * i + 1] = (_Float16)tanhf(0.5f * v.y);
        t_sh[4 * i + 2] = (_Float16)tanhf(0.5f * v.z);
        t_sh[4 * i + 3] = (_Float16)tanhf(0.5f * v.w);
    }
    __syncthreads();

    // Check-node part: bce = ln2 - log1p(y ? -p : p)
    float sum = 0.0f;
    const float* syn_row = syndromes + (size_t)b * M_;
    for (int m = tid; m < M_; m += 256) {
        const int4* cc = reinterpret_cast<const int4*>(chk_cols) + 2 * m;
        int4 c0 = cc[0];
        int4 c1 = cc[1];
        float p01 = (float)t_sh[c0.x] * (float)t_sh[c0.y];
        float p23 = (float)t_sh[c0.z] * (float)t_sh[c0.w];
        float p45 = (float)t_sh[c1.x] * (float)t_sh[c1.y];
        float p67 = (float)t_sh[c1.z] * (float)t_sh[c1.w];
        float p = (p01 * p23) * (p45 * p67);
        p = fminf(fmaxf(p, -1.0f + EPS_), 1.0f - EPS_);
        float y   = syn_row[m];
        float arg = (y > 0.5f) ? -p : p;
        sum += LN2_ - log1pf(arg);
    }
    sum *= 0.5f;  // BETA

    // Observable part (tiny): threads 0..7 each handle one k.
    if (tid < K_) {
        const int* oc = obs_cols + tid * OBS_W_;
        float p = 1.0f;
        for (int w = 0; w < OBS_W_; ++w) p *= (float)t_sh[oc[w]];
        p = fminf(fmaxf(p, -1.0f + EPS_), 1.0f - EPS_);
        float y   = observables[(size_t)b * K_ + tid];
        float arg = (y > 0.5f) ? -p : p;
        sum += 0.5f * (LN2_ - log1pf(arg));  // (1-BETA)
    }

    // Block reduction: wave shuffle + 4-entry LDS.
    for (int off = 32; off > 0; off >>= 1) sum += __shfl_down(sum, off, 64);
    const int lane = tid & 63, wv = tid >> 6;
    if (lane == 0) red[wv] = sum;
    __syncthreads();
    if (tid == 0) {
        float tot = red[0] + red[1] + red[2] + red[3];
        if (ATOMIC) {
            atomicAdd(part, tot * (1.0f / (float)B_));
        } else {
            part[b] = tot;
        }
    }
}

__global__ __launch_bounds__(256) void decode_loss_reduce(
    const float* __restrict__ part, float* __restrict__ out)
{
    __shared__ float red[4];
    const int tid = threadIdx.x;
    float s = 0.0f;
    for (int i = tid; i < B_; i += 256) s += part[i];
    for (int off = 32; off > 0; off >>= 1) s += __shfl_down(s, off, 64);
    const int lane = tid & 63, wv = tid >> 6;
    if (lane == 0) red[wv] = s;
    __syncthreads();
    if (tid == 0) out[0] = (red[0] + red[1] + red[2] + red[3]) * (1.0f / (float)B_);
}

extern "C" void kernel_launch(void* const* d_in, const int* in_sizes, int n_in,
                              void* d_out, int out_size, void* d_ws, size_t ws_size,
                              hipStream_t stream) {
    const float* llrs        = (const float*)d_in[0];
    const float* syndromes   = (const float*)d_in[1];
    const float* observables = (const float*)d_in[2];
    const int*   chk_cols    = (const int*)d_in[3];
    const int*   obs_cols    = (const int*)d_in[4];
    float*       out         = (float*)d_out;

    if (ws_size >= (size_t)B_ * sizeof(float)) {
        float* part = (float*)d_ws;
        decode_loss_main<false><<<B_, 256, 0, stream>>>(
            llrs, syndromes, observables, chk_cols, obs_cols, part);
        decode_loss_reduce<<<1, 256, 0, stream>>>(part, out);
    } else {
        hipMemsetAsync(out, 0, sizeof(float), stream);
        decode_loss_main<true><<<B_, 256, 0, stream>>>(
            llrs, syndromes, observables, chk_cols, obs_cols, out);
    }
}

// Round 2
// 37.392 us; speedup vs baseline: 1.8288x; 1.8288x over previous
//
#include <hip/hip_runtime.h>

#define B_ 1024
#define N_ 20000
#define M_ 10000
#define K_ 8
#define OBS_W_ 200
#define TPB 512

constexpr float EPS_   = 1e-6f;
constexpr float LN2_   = 0.69314718055994530942f;
constexpr float LOG2E_ = 1.4426950408889634f;

// tanh(x/2) = 1 - 2/(exp(x)+1), via hardware v_exp_f32 / v_rcp_f32.
__device__ __forceinline__ float tanh_half_fast(float x) {
    float e = __builtin_amdgcn_exp2f(x * LOG2E_);
    return 1.0f - 2.0f * __builtin_amdgcn_rcpf(e + 1.0f);
}

template <bool ATOMIC>
__global__ __launch_bounds__(TPB) void decode_loss_main(
    const float* __restrict__ llrs,
    const float* __restrict__ syndromes,
    const float* __restrict__ observables,
    const int*   __restrict__ chk_cols,
    const int*   __restrict__ obs_cols,
    float* __restrict__ part)
{
    __shared__ _Float16 t_sh[N_];
    __shared__ float red[TPB / 64];

    const int b   = blockIdx.x;
    const int tid = threadIdx.x;

    // Stage tanh(llr/2) row into LDS as fp16 (40 KB).
    const float4* row4 = reinterpret_cast<const float4*>(llrs + (size_t)b * N_);
    for (int i = tid; i < N_ / 4; i += TPB) {
        float4 v = row4[i];
        t_sh[4 * i + 0] = (_Float16)tanh_half_fast(v.x);
        t_sh[4 * i + 1] = (_Float16)tanh_half_fast(v.y);
        t_sh[4 * i + 2] = (_Float16)tanh_half_fast(v.z);
        t_sh[4 * i + 3] = (_Float16)tanh_half_fast(v.w);
    }
    __syncthreads();

    // Check part: bce(y, -L) = ln2 - ln(1 + (1-2y)*p) = LN2*(1 - log2(w))
    float acc = 0.0f;   // sum of log2(w)
    int   cnt = 0;
    const float* syn_row = syndromes + (size_t)b * M_;
    const int4*  cc      = reinterpret_cast<const int4*>(chk_cols);
    for (int m = tid; m < M_; m += TPB) {
        int4 c0 = cc[2 * m];
        int4 c1 = cc[2 * m + 1];
        float p01 = (float)t_sh[c0.x] * (float)t_sh[c0.y];
        float p23 = (float)t_sh[c0.z] * (float)t_sh[c0.w];
        float p45 = (float)t_sh[c1.x] * (float)t_sh[c1.y];
        float p67 = (float)t_sh[c1.z] * (float)t_sh[c1.w];
        float p = (p01 * p23) * (p45 * p67);
        p = fminf(fmaxf(p, -1.0f + EPS_), 1.0f - EPS_);
        float sgn = 1.0f - 2.0f * syn_row[m];       // y=1 -> -1, y=0 -> +1
        float w   = fmaf(sgn, p, 1.0f);             // 1 + sgn*p
        acc += __builtin_amdgcn_logf(w);            // log2(w)
        ++cnt;
    }
    float sum = 0.5f * LN2_ * ((float)cnt - acc);   // BETA = 0.5

    // Obs part: one wave; 8 lanes per k, 25 elements each, shuffle-mul reduce.
    if (tid < 64) {
        const int k   = tid >> 3;
        const int seg = tid & 7;
        const int* oc = obs_cols + k * OBS_W_ + seg * 25;
        float pr = 1.0f;
        #pragma unroll
        for (int w = 0; w < 25; ++w) pr *= (float)t_sh[oc[w]];
        #pragma unroll
        for (int off = 1; off < 8; off <<= 1) pr *= __shfl_xor(pr, off, 64);
        if (seg == 0) {
            float p = fminf(fmaxf(pr, -1.0f + EPS_), 1.0f - EPS_);
            float sgn = 1.0f - 2.0f * observables[(size_t)b * K_ + k];
            float w2  = fmaf(sgn, p, 1.0f);
            sum += 0.5f * LN2_ * (1.0f - __builtin_amdgcn_logf(w2));  // 1-BETA
        }
    }

    // Block reduction.
    for (int off = 32; off > 0; off >>= 1) sum += __shfl_down(sum, off, 64);
    const int lane = tid & 63, wv = tid >> 6;
    if (lane == 0) red[wv] = sum;
    __syncthreads();
    if (tid == 0) {
        float tot = 0.0f;
        #pragma unroll
        for (int i = 0; i < TPB / 64; ++i) tot += red[i];
        if (ATOMIC) {
            atomicAdd(part, tot * (1.0f / (float)B_));
        } else {
            part[b] = tot;
        }
    }
}

__global__ __launch_bounds__(256) void decode_loss_reduce(
    const float* __restrict__ part, float* __restrict__ out)
{
    __shared__ float red[4];
    const int tid = threadIdx.x;
    float s = 0.0f;
    for (int i = tid; i < B_; i += 256) s += part[i];
    for (int off = 32; off > 0; off >>= 1) s += __shfl_down(s, off, 64);
    const int lane = tid & 63, wv = tid >> 6;
    if (lane == 0) red[wv] = s;
    __syncthreads();
    if (tid == 0) out[0] = (red[0] + red[1] + red[2] + red[3]) * (1.0f / (float)B_);
}

extern "C" void kernel_launch(void* const* d_in, const int* in_sizes, int n_in,
                              void* d_out, int out_size, void* d_ws, size_t ws_size,
                              hipStream_t stream) {
    const float* llrs        = (const float*)d_in[0];
    const float* syndromes   = (const float*)d_in[1];
    const float* observables = (const float*)d_in[2];
    const int*   chk_cols    = (const int*)d_in[3];
    const int*   obs_cols    = (const int*)d_in[4];
    float*       out         = (float*)d_out;

    if (ws_size >= (size_t)B_ * sizeof(float)) {
        float* part = (float*)d_ws;
        decode_loss_main<false><<<B_, TPB, 0, stream>>>(
            llrs, syndromes, observables, chk_cols, obs_cols, part);
        decode_loss_reduce<<<1, 256, 0, stream>>>(part, out);
    } else {
        hipMemsetAsync(out, 0, sizeof(float), stream);
        decode_loss_main<true><<<B_, TPB, 0, stream>>>(
            llrs, syndromes, observables, chk_cols, obs_cols, out);
    }
}

// Round 3
// 29.740 us; speedup vs baseline: 2.2994x; 1.2573x over previous
//
#include <hip/hip_runtime.h>

#define B_ 1024
#define N_ 20000
#define M_ 10000
#define K_ 8
#define OBS_W_ 200
#define TPB 1024

constexpr float EPS_   = 1e-6f;
constexpr float LN2_   = 0.69314718055994530942f;
constexpr float LOG2E_ = 1.4426950408889634f;

typedef _Float16 f16x2 __attribute__((ext_vector_type(2)));
typedef _Float16 f16x8 __attribute__((ext_vector_type(8)));

// tanh(x/2) = 1 - 2/(exp(x)+1), via hardware v_exp_f32 / v_rcp_f32.
__device__ __forceinline__ float tanh_half_fast(float x) {
    float e = __builtin_amdgcn_exp2f(x * LOG2E_);
    return 1.0f - 2.0f * __builtin_amdgcn_rcpf(e + 1.0f);
}

// Two batch rows per block, interleaved f16 pairs in LDS (80 KB dynamic).
template <bool ATOMIC>
__global__ __launch_bounds__(TPB) void decode_loss_main2(
    const float* __restrict__ llrs,
    const float* __restrict__ syndromes,
    const float* __restrict__ observables,
    const int*   __restrict__ chk_cols,
    const int*   __restrict__ obs_cols,
    float* __restrict__ part)
{
    extern __shared__ char smem_raw[];
    f16x2* t2 = reinterpret_cast<f16x2*>(smem_raw);
    __shared__ float red0[TPB / 64], red1[TPB / 64];

    const int b0  = 2 * blockIdx.x;
    const int b1  = b0 + 1;
    const int tid = threadIdx.x;

    // Stage tanh(llr/2) for both rows, interleaved: one ds_write_b128 per 4 n.
    const float4* r0 = reinterpret_cast<const float4*>(llrs + (size_t)b0 * N_);
    const float4* r1 = reinterpret_cast<const float4*>(llrs + (size_t)b1 * N_);
    for (int i = tid; i < N_ / 4; i += TPB) {
        float4 a = r0[i];
        float4 c = r1[i];
        f16x8 v;
        v[0] = (_Float16)tanh_half_fast(a.x); v[1] = (_Float16)tanh_half_fast(c.x);
        v[2] = (_Float16)tanh_half_fast(a.y); v[3] = (_Float16)tanh_half_fast(c.y);
        v[4] = (_Float16)tanh_half_fast(a.z); v[5] = (_Float16)tanh_half_fast(c.z);
        v[6] = (_Float16)tanh_half_fast(a.w); v[7] = (_Float16)tanh_half_fast(c.w);
        *reinterpret_cast<f16x8*>(&t2[4 * i]) = v;
    }
    __syncthreads();

    // Check part for both rows: one b32 gather yields both rows' factors.
    float acc0 = 0.0f, acc1 = 0.0f;
    int   cnt  = 0;
    const float* syn0 = syndromes + (size_t)b0 * M_;
    const float* syn1 = syndromes + (size_t)b1 * M_;
    const int4*  cc   = reinterpret_cast<const int4*>(chk_cols);
    for (int m = tid; m < M_; m += TPB) {
        int4 c0 = cc[2 * m];
        int4 c1 = cc[2 * m + 1];
        f16x2 g0 = t2[c0.x], g1 = t2[c0.y], g2 = t2[c0.z], g3 = t2[c0.w];
        f16x2 g4 = t2[c1.x], g5 = t2[c1.y], g6 = t2[c1.z], g7 = t2[c1.w];
        f16x2 p  = ((g0 * g1) * (g2 * g3)) * ((g4 * g5) * (g6 * g7));
        float pa = (float)p[0];
        float pb = (float)p[1];
        pa = fminf(fmaxf(pa, -1.0f + EPS_), 1.0f - EPS_);
        pb = fminf(fmaxf(pb, -1.0f + EPS_), 1.0f - EPS_);
        float w0 = fmaf(1.0f - 2.0f * syn0[m], pa, 1.0f);
        float w1 = fmaf(1.0f - 2.0f * syn1[m], pb, 1.0f);
        acc0 += __builtin_amdgcn_logf(w0);   // log2(w)
        acc1 += __builtin_amdgcn_logf(w1);
        ++cnt;
    }
    float sum0 = 0.5f * LN2_ * ((float)cnt - acc0);   // BETA = 0.5
    float sum1 = 0.5f * LN2_ * ((float)cnt - acc1);

    // Obs part: 2 waves; (row, k) per 8-lane group, 25 elems per lane.
    if (tid < 128) {
        const int row = tid >> 6;          // 0 or 1
        const int k   = (tid >> 3) & 7;
        const int seg = tid & 7;
        const int* oc = obs_cols + k * OBS_W_ + seg * 25;
        float pr = 1.0f;
        #pragma unroll 5
        for (int w = 0; w < 25; ++w) {
            f16x2 g = t2[oc[w]];
            pr *= (float)g[row];
        }
        #pragma unroll
        for (int off = 1; off < 8; off <<= 1) pr *= __shfl_xor(pr, off, 64);
        if (seg == 0) {
            const int bb = row == 0 ? b0 : b1;
            float p = fminf(fmaxf(pr, -1.0f + EPS_), 1.0f - EPS_);
            float sgn = 1.0f - 2.0f * observables[(size_t)bb * K_ + k];
            float w2  = fmaf(sgn, p, 1.0f);
            float v   = 0.5f * LN2_ * (1.0f - __builtin_amdgcn_logf(w2)); // 1-BETA
            if (row == 0) sum0 += v; else sum1 += v;
        }
    }

    // Block reduction of both row-sums.
    for (int off = 32; off > 0; off >>= 1) {
        sum0 += __shfl_down(sum0, off, 64);
        sum1 += __shfl_down(sum1, off, 64);
    }
    const int lane = tid & 63, wv = tid >> 6;
    if (lane == 0) { red0[wv] = sum0; red1[wv] = sum1; }
    __syncthreads();
    if (tid == 0) {
        float tot = 0.0f;
        #pragma unroll
        for (int i = 0; i < TPB / 64; ++i) tot += red0[i] + red1[i];
        if (ATOMIC) {
            atomicAdd(part, tot * (1.0f / (float)B_));
        } else {
            part[blockIdx.x] = tot;   // sum of both rows' losses
        }
    }
}

__global__ __launch_bounds__(256) void decode_loss_reduce(
    const float* __restrict__ part, float* __restrict__ out, int n)
{
    __shared__ float red[4];
    const int tid = threadIdx.x;
    float s = 0.0f;
    for (int i = tid; i < n; i += 256) s += part[i];
    for (int off = 32; off > 0; off >>= 1) s += __shfl_down(s, off, 64);
    const int lane = tid & 63, wv = tid >> 6;
    if (lane == 0) red[wv] = s;
    __syncthreads();
    if (tid == 0) out[0] = (red[0] + red[1] + red[2] + red[3]) * (1.0f / (float)B_);
}

extern "C" void kernel_launch(void* const* d_in, const int* in_sizes, int n_in,
                              void* d_out, int out_size, void* d_ws, size_t ws_size,
                              hipStream_t stream) {
    const float* llrs        = (const float*)d_in[0];
    const float* syndromes   = (const float*)d_in[1];
    const float* observables = (const float*)d_in[2];
    const int*   chk_cols    = (const int*)d_in[3];
    const int*   obs_cols    = (const int*)d_in[4];
    float*       out         = (float*)d_out;

    const size_t lds_bytes = (size_t)N_ * sizeof(f16x2);   // 80 000 B

    // Opt in to >64 KB dynamic LDS (idempotent; safe under graph capture).
    static_assert(sizeof(f16x2) == 4, "");
    {
        auto kf = decode_loss_main2<false>;
        auto kt = decode_loss_main2<true>;
        (void)hipFuncSetAttribute((const void*)kf,
            hipFuncAttributeMaxDynamicSharedMemorySize, (int)lds_bytes);
        (void)hipFuncSetAttribute((const void*)kt,
            hipFuncAttributeMaxDynamicSharedMemorySize, (int)lds_bytes);
    }

    const int nblk = B_ / 2;
    if (ws_size >= (size_t)nblk * sizeof(float)) {
        float* part = (float*)d_ws;
        decode_loss_main2<false><<<nblk, TPB, lds_bytes, stream>>>(
            llrs, syndromes, observables, chk_cols, obs_cols, part);
        decode_loss_reduce<<<1, 256, 0, stream>>>(part, out, nblk);
    } else {
        hipMemsetAsync(out, 0, sizeof(float), stream);
        decode_loss_main2<true><<<nblk, TPB, lds_bytes, stream>>>(
            llrs, syndromes, observables, chk_cols, obs_cols, out);
    }
}

// Round 4
// 26.689 us; speedup vs baseline: 2.5622x; 1.1143x over previous
//
#include <hip/hip_runtime.h>

#define B_ 1024
#define N_ 20000
#define M_ 10000
#define K_ 8
#define OBS_W_ 200
#define TPB 1024

constexpr float EPS_   = 1e-6f;
constexpr float LN2_   = 0.69314718055994530942f;
constexpr float LOG2E_ = 1.4426950408889634f;

typedef _Float16 f16x2 __attribute__((ext_vector_type(2)));
typedef _Float16 f16x4 __attribute__((ext_vector_type(4)));
typedef _Float16 f16x8 __attribute__((ext_vector_type(8)));

// tanh(x/2) = 1 - 2/(exp(x)+1), via hardware v_exp_f32 / v_rcp_f32.
__device__ __forceinline__ float tanh_half_fast(float x) {
    float e = __builtin_amdgcn_exp2f(x * LOG2E_);
    return 1.0f - 2.0f * __builtin_amdgcn_rcpf(e + 1.0f);
}

__device__ __forceinline__ float bce_term(float p, float y) {
    // ln2 - log1p((1-2y)*p), accumulated as log2; caller applies LN2*(cnt-acc).
    p = fminf(fmaxf(p, -1.0f + EPS_), 1.0f - EPS_);
    float w = fmaf(1.0f - 2.0f * y, p, 1.0f);
    return __builtin_amdgcn_logf(w);   // log2(w)
}

// ---------------- 4 rows per block, f16x4 in 160 KB dynamic LDS -------------
template <bool ATOMIC>
__global__ __launch_bounds__(TPB) void decode_loss_main4(
    const float* __restrict__ llrs,
    const float* __restrict__ syndromes,
    const float* __restrict__ observables,
    const int*   __restrict__ chk_cols,
    const int*   __restrict__ obs_cols,
    float* __restrict__ part)
{
    extern __shared__ char smem_raw[];
    f16x4* t4 = reinterpret_cast<f16x4*>(smem_raw);
    __shared__ float red[TPB / 64];

    const int b0  = 4 * blockIdx.x;
    const int tid = threadIdx.x;

    // Stage tanh(llr/2) for 4 rows, interleaved: t4[n] = {r0,r1,r2,r3}(n).
    const float4* r0 = reinterpret_cast<const float4*>(llrs + (size_t)(b0 + 0) * N_);
    const float4* r1 = reinterpret_cast<const float4*>(llrs + (size_t)(b0 + 1) * N_);
    const float4* r2 = reinterpret_cast<const float4*>(llrs + (size_t)(b0 + 2) * N_);
    const float4* r3 = reinterpret_cast<const float4*>(llrs + (size_t)(b0 + 3) * N_);
    for (int i = tid; i < N_ / 4; i += TPB) {
        float4 a = r0[i], b = r1[i], c = r2[i], d = r3[i];
        f16x8 w01, w23;
        w01[0] = (_Float16)tanh_half_fast(a.x); w01[1] = (_Float16)tanh_half_fast(b.x);
        w01[2] = (_Float16)tanh_half_fast(c.x); w01[3] = (_Float16)tanh_half_fast(d.x);
        w01[4] = (_Float16)tanh_half_fast(a.y); w01[5] = (_Float16)tanh_half_fast(b.y);
        w01[6] = (_Float16)tanh_half_fast(c.y); w01[7] = (_Float16)tanh_half_fast(d.y);
        w23[0] = (_Float16)tanh_half_fast(a.z); w23[1] = (_Float16)tanh_half_fast(b.z);
        w23[2] = (_Float16)tanh_half_fast(c.z); w23[3] = (_Float16)tanh_half_fast(d.z);
        w23[4] = (_Float16)tanh_half_fast(a.w); w23[5] = (_Float16)tanh_half_fast(b.w);
        w23[6] = (_Float16)tanh_half_fast(c.w); w23[7] = (_Float16)tanh_half_fast(d.w);
        *reinterpret_cast<f16x8*>(&t4[4 * i + 0]) = w01;
        *reinterpret_cast<f16x8*>(&t4[4 * i + 2]) = w23;
    }
    __syncthreads();

    // Check part: one b64 gather yields all 4 rows' factors.
    float acc = 0.0f;   // sum of log2(w) over all rows handled
    int   cnt = 0;
    const float* syn0 = syndromes + (size_t)(b0 + 0) * M_;
    const float* syn1 = syndromes + (size_t)(b0 + 1) * M_;
    const float* syn2 = syndromes + (size_t)(b0 + 2) * M_;
    const float* syn3 = syndromes + (size_t)(b0 + 3) * M_;
    const int4*  cc   = reinterpret_cast<const int4*>(chk_cols);
    for (int m = tid; m < M_; m += TPB) {
        int4 c0 = cc[2 * m];
        int4 c1 = cc[2 * m + 1];
        f16x4 g0 = t4[c0.x], g1 = t4[c0.y], g2 = t4[c0.z], g3 = t4[c0.w];
        f16x4 g4 = t4[c1.x], g5 = t4[c1.y], g6 = t4[c1.z], g7 = t4[c1.w];
        f16x4 p  = ((g0 * g1) * (g2 * g3)) * ((g4 * g5) * (g6 * g7));
        acc += bce_term((float)p[0], syn0[m]);
        acc += bce_term((float)p[1], syn1[m]);
        acc += bce_term((float)p[2], syn2[m]);
        acc += bce_term((float)p[3], syn3[m]);
        ++cnt;
    }
    // BETA = 0.5 applied; 4 rows share cnt.
    float sum = 0.5f * LN2_ * (4.0f * (float)cnt - acc);

    // Obs part: 4 waves; wave=row, 8 lanes per k, 25 elems per lane.
    if (tid < 256) {
        const int row = tid >> 6;          // 0..3
        const int k   = (tid >> 3) & 7;
        const int seg = tid & 7;
        const int* oc = obs_cols + k * OBS_W_ + seg * 25;
        float pr = 1.0f;
        #pragma unroll 5
        for (int w = 0; w < 25; ++w) {
            f16x4 g = t4[oc[w]];
            pr *= (float)g[row];
        }
        #pragma unroll
        for (int off = 1; off < 8; off <<= 1) pr *= __shfl_xor(pr, off, 64);
        if (seg == 0) {
            float y = observables[(size_t)(b0 + row) * K_ + k];
            // 1-BETA = 0.5; single term: 0.5*LN2*(1 - log2(w))
            sum += 0.5f * LN2_ * (1.0f - bce_term(pr, y));
        }
    }

    // Block reduction.
    for (int off = 32; off > 0; off >>= 1) sum += __shfl_down(sum, off, 64);
    const int lane = tid & 63, wv = tid >> 6;
    if (lane == 0) red[wv] = sum;
    __syncthreads();
    if (tid == 0) {
        float tot = 0.0f;
        #pragma unroll
        for (int i = 0; i < TPB / 64; ++i) tot += red[i];
        if (ATOMIC) atomicAdd(part, tot * (1.0f / (float)B_));
        else        part[blockIdx.x] = tot;
    }
}

// ---------------- fallback: 2 rows per block, 80 KB (proven R3 path) --------
template <bool ATOMIC>
__global__ __launch_bounds__(TPB) void decode_loss_main2(
    const float* __restrict__ llrs,
    const float* __restrict__ syndromes,
    const float* __restrict__ observables,
    const int*   __restrict__ chk_cols,
    const int*   __restrict__ obs_cols,
    float* __restrict__ part)
{
    extern __shared__ char smem_raw[];
    f16x2* t2 = reinterpret_cast<f16x2*>(smem_raw);
    __shared__ float red[TPB / 64];

    const int b0  = 2 * blockIdx.x;
    const int tid = threadIdx.x;

    const float4* r0 = reinterpret_cast<const float4*>(llrs + (size_t)b0 * N_);
    const float4* r1 = reinterpret_cast<const float4*>(llrs + (size_t)(b0 + 1) * N_);
    for (int i = tid; i < N_ / 4; i += TPB) {
        float4 a = r0[i], c = r1[i];
        f16x8 v;
        v[0] = (_Float16)tanh_half_fast(a.x); v[1] = (_Float16)tanh_half_fast(c.x);
        v[2] = (_Float16)tanh_half_fast(a.y); v[3] = (_Float16)tanh_half_fast(c.y);
        v[4] = (_Float16)tanh_half_fast(a.z); v[5] = (_Float16)tanh_half_fast(c.z);
        v[6] = (_Float16)tanh_half_fast(a.w); v[7] = (_Float16)tanh_half_fast(c.w);
        *reinterpret_cast<f16x8*>(&t2[4 * i]) = v;
    }
    __syncthreads();

    float acc = 0.0f;
    int   cnt = 0;
    const float* syn0 = syndromes + (size_t)b0 * M_;
    const float* syn1 = syndromes + (size_t)(b0 + 1) * M_;
    const int4*  cc   = reinterpret_cast<const int4*>(chk_cols);
    for (int m = tid; m < M_; m += TPB) {
        int4 c0 = cc[2 * m];
        int4 c1 = cc[2 * m + 1];
        f16x2 g0 = t2[c0.x], g1 = t2[c0.y], g2 = t2[c0.z], g3 = t2[c0.w];
        f16x2 g4 = t2[c1.x], g5 = t2[c1.y], g6 = t2[c1.z], g7 = t2[c1.w];
        f16x2 p  = ((g0 * g1) * (g2 * g3)) * ((g4 * g5) * (g6 * g7));
        acc += bce_term((float)p[0], syn0[m]);
        acc += bce_term((float)p[1], syn1[m]);
        ++cnt;
    }
    float sum = 0.5f * LN2_ * (2.0f * (float)cnt - acc);

    if (tid < 128) {
        const int row = tid >> 6;
        const int k   = (tid >> 3) & 7;
        const int seg = tid & 7;
        const int* oc = obs_cols + k * OBS_W_ + seg * 25;
        float pr = 1.0f;
        #pragma unroll 5
        for (int w = 0; w < 25; ++w) { f16x2 g = t2[oc[w]]; pr *= (float)g[row]; }
        #pragma unroll
        for (int off = 1; off < 8; off <<= 1) pr *= __shfl_xor(pr, off, 64);
        if (seg == 0) {
            float y = observables[(size_t)(b0 + row) * K_ + k];
            sum += 0.5f * LN2_ * (1.0f - bce_term(pr, y));
        }
    }

    for (int off = 32; off > 0; off >>= 1) sum += __shfl_down(sum, off, 64);
    const int lane = tid & 63, wv = tid >> 6;
    if (lane == 0) red[wv] = sum;
    __syncthreads();
    if (tid == 0) {
        float tot = 0.0f;
        #pragma unroll
        for (int i = 0; i < TPB / 64; ++i) tot += red[i];
        if (ATOMIC) atomicAdd(part, tot * (1.0f / (float)B_));
        else        part[blockIdx.x] = tot;
    }
}

__global__ __launch_bounds__(256) void decode_loss_reduce(
    const float* __restrict__ part, float* __restrict__ out, int n)
{
    __shared__ float red[4];
    const int tid = threadIdx.x;
    float s = 0.0f;
    for (int i = tid; i < n; i += 256) s += part[i];
    for (int off = 32; off > 0; off >>= 1) s += __shfl_down(s, off, 64);
    const int lane = tid & 63, wv = tid >> 6;
    if (lane == 0) red[wv] = s;
    __syncthreads();
    if (tid == 0) out[0] = (red[0] + red[1] + red[2] + red[3]) * (1.0f / (float)B_);
}

extern "C" void kernel_launch(void* const* d_in, const int* in_sizes, int n_in,
                              void* d_out, int out_size, void* d_ws, size_t ws_size,
                              hipStream_t stream) {
    const float* llrs        = (const float*)d_in[0];
    const float* syndromes   = (const float*)d_in[1];
    const float* observables = (const float*)d_in[2];
    const int*   chk_cols    = (const int*)d_in[3];
    const int*   obs_cols    = (const int*)d_in[4];
    float*       out         = (float*)d_out;

    const size_t lds4 = (size_t)N_ * sizeof(f16x4);   // 160 000 B
    const size_t lds2 = (size_t)N_ * sizeof(f16x2);   //  80 000 B

    hipError_t e4 = hipFuncSetAttribute((const void*)decode_loss_main4<false>,
        hipFuncAttributeMaxDynamicSharedMemorySize, (int)lds4);
    (void)hipFuncSetAttribute((const void*)decode_loss_main4<true>,
        hipFuncAttributeMaxDynamicSharedMemorySize, (int)lds4);

    const bool use4 = (e4 == hipSuccess);
    if (!use4) {
        (void)hipFuncSetAttribute((const void*)decode_loss_main2<false>,
            hipFuncAttributeMaxDynamicSharedMemorySize, (int)lds2);
        (void)hipFuncSetAttribute((const void*)decode_loss_main2<true>,
            hipFuncAttributeMaxDynamicSharedMemorySize, (int)lds2);
    }

    const int nblk = use4 ? B_ / 4 : B_ / 2;
    if (ws_size >= (size_t)nblk * sizeof(float)) {
        float* part = (float*)d_ws;
        if (use4)
            decode_loss_main4<false><<<nblk, TPB, lds4, stream>>>(
                llrs, syndromes, observables, chk_cols, obs_cols, part);
        else
            decode_loss_main2<false><<<nblk, TPB, lds2, stream>>>(
                llrs, syndromes, observables, chk_cols, obs_cols, part);
        decode_loss_reduce<<<1, 256, 0, stream>>>(part, out, nblk);
    } else {
        hipMemsetAsync(out, 0, sizeof(float), stream);
        if (use4)
            decode_loss_main4<true><<<nblk, TPB, lds4, stream>>>(
                llrs, syndromes, observables, chk_cols, obs_cols, out);
        else
            decode_loss_main2<true><<<nblk, TPB, lds2, stream>>>(
                llrs, syndromes, observables, chk_cols, obs_cols, out);
    }
}